// Round 1
// baseline (382.072 us; speedup 1.0000x reference)
//
#include <hip/hip_runtime.h>
#include <hip/hip_bf16.h>

typedef unsigned short u16;
typedef __bf16 bf16x8 __attribute__((ext_vector_type(8)));
typedef float f32x4 __attribute__((ext_vector_type(4)));

#define T_TOK 1024
#define HID   2048
#define IMM   768
#define NE    8
#define TWOI  1536
#define KTOT  6144   // NE*IMM

static __device__ __forceinline__ u16 f2bf(float f) {
  unsigned u = __float_as_uint(f);
  u += 0x7FFFu + ((u >> 16) & 1u);   // RNE
  return (u16)(u >> 16);
}
static __device__ __forceinline__ float bf2f(u16 s) {
  return __uint_as_float(((unsigned)s) << 16);
}

// ---------------- router: logits -> softmax -> top2 -> renorm -> comb[T][E]
__global__ __launch_bounds__(64) void router_kernel(
    const float* __restrict__ hid, const float* __restrict__ gw,
    float* __restrict__ comb)
{
  const int t = blockIdx.x;
  const int lane = threadIdx.x;
  float acc[NE];
#pragma unroll
  for (int e = 0; e < NE; ++e) acc[e] = 0.f;
  const float4* h4 = (const float4*)(hid + (long)t * HID);
#pragma unroll 2
  for (int c = lane; c < HID / 4; c += 64) {
    float4 x = h4[c];
#pragma unroll
    for (int e = 0; e < NE; ++e) {
      float4 w = ((const float4*)(gw + e * HID))[c];
      acc[e] += x.x * w.x + x.y * w.y + x.z * w.z + x.w * w.w;
    }
  }
#pragma unroll
  for (int e = 0; e < NE; ++e) {
    float v = acc[e];
#pragma unroll
    for (int off = 32; off > 0; off >>= 1) v += __shfl_xor(v, off, 64);
    acc[e] = v;
  }
  if (lane == 0) {
    float mx = acc[0];
#pragma unroll
    for (int e = 1; e < NE; ++e) mx = fmaxf(mx, acc[e]);
    float p[NE]; float s = 0.f;
#pragma unroll
    for (int e = 0; e < NE; ++e) { p[e] = expf(acc[e] - mx); s += p[e]; }
    const float inv = 1.f / s;
    float p1 = -1.f, p2 = -1.f; int i1 = 0, i2 = 0;
#pragma unroll
    for (int e = 0; e < NE; ++e) {
      float pe = p[e] * inv;
      if (pe > p1)      { p2 = p1; i2 = i1; p1 = pe; i1 = e; }
      else if (pe > p2) { p2 = pe; i2 = e; }
    }
    const float wsum = p1 + p2;
    float cw[NE];
#pragma unroll
    for (int e = 0; e < NE; ++e) cw[e] = 0.f;
    cw[i1] = p1 / wsum;
    cw[i2] = p2 / wsum;
#pragma unroll
    for (int e = 0; e < NE; ++e) comb[t * NE + e] = cw[e];
  }
}

// ---------------- hidden fp32 -> bf16
__global__ __launch_bounds__(256) void cvt_kernel(
    const float* __restrict__ in, u16* __restrict__ out)
{
  const int i = blockIdx.x * 256 + threadIdx.x;   // grid sized exactly: T*H/4 threads
  float4 x = ((const float4*)in)[i];
  ushort4 o;
  o.x = f2bf(x.x); o.y = f2bf(x.y); o.z = f2bf(x.z); o.w = f2bf(x.w);
  ((ushort4*)out)[i] = o;
}

// ---------------- B^T GEMM: C[m,n] = sum_k A[m,k]*B[n,k]
// A bf16 [.,lda] (+ per-z element offset a_zoff), B fp32 rows of length K (+ b_zoff per z),
// C either bf16 store (Cb) or fp32 atomicAdd (Cf). 128x128 tile, BK=32, 256 thr / 4 waves.
template<int K, bool OUT_ATOMIC>
__global__ __launch_bounds__(256, 2) void gemm_bt(
    const u16* __restrict__ A, int lda, long a_zoff,
    const float* __restrict__ B, long b_zoff,
    u16* __restrict__ Cb, float* __restrict__ Cf, int ldc, long c_zoff)
{
  constexpr int BM = 128, BN = 128, BK = 32;
  constexpr int LSTR = BK + 8;        // +16B pad: breaks 64B-stride bank pattern
  constexpr int NKT = K / BK;
  static_assert(NKT >= 2 && (K % BK) == 0, "K must be multiple of 32, >=64");
  __shared__ __align__(16) u16 As[2][BM * LSTR];
  __shared__ __align__(16) u16 Bs[2][BN * LSTR];

  const int tid  = threadIdx.x;
  const int lane = tid & 63;
  const int wave = tid >> 6;
  const int wm = wave >> 1, wn = wave & 1;   // 2x2 waves, each 64x64 out
  const int lrow = lane & 15;
  const int lk   = (lane >> 4) << 3;         // 8 contiguous k per lane

  const int z = blockIdx.z;
  const long m0 = (long)blockIdx.x * BM;
  const long n0 = (long)blockIdx.y * BN;

  const u16*   Ab = A + a_zoff * z + m0 * lda;
  const float* Bb = B + b_zoff * z + n0 * (long)K;

  // staging: 512 chunks of 8 elems (128 rows x 4 col-segments); thread owns rows r0, r0+64
  const int r0  = tid >> 2;
  const int cs0 = (tid & 3) << 3;

  uint4 sa0, sa1; float4 sb0a, sb0b, sb1a, sb1b;

  auto gload = [&](int kk) {
    const u16* ap = Ab + (long)r0 * lda + kk + cs0;
    sa0 = *(const uint4*)ap;
    sa1 = *(const uint4*)(ap + 64l * lda);
    const float* bp = Bb + (long)r0 * K + kk + cs0;
    sb0a = *(const float4*)bp;
    sb0b = *(const float4*)(bp + 4);
    sb1a = *(const float4*)(bp + 64l * K);
    sb1b = *(const float4*)(bp + 64l * K + 4);
  };
  auto packb = [&](const float4& f0, const float4& f1) -> uint4 {
    return make_uint4(
      (unsigned)f2bf(f0.x) | ((unsigned)f2bf(f0.y) << 16),
      (unsigned)f2bf(f0.z) | ((unsigned)f2bf(f0.w) << 16),
      (unsigned)f2bf(f1.x) | ((unsigned)f2bf(f1.y) << 16),
      (unsigned)f2bf(f1.z) | ((unsigned)f2bf(f1.w) << 16));
  };
  auto swrite = [&](int buf) {
    *(uint4*)&As[buf][r0 * LSTR + cs0]        = sa0;
    *(uint4*)&As[buf][(r0 + 64) * LSTR + cs0] = sa1;
    *(uint4*)&Bs[buf][r0 * LSTR + cs0]        = packb(sb0a, sb0b);
    *(uint4*)&Bs[buf][(r0 + 64) * LSTR + cs0] = packb(sb1a, sb1b);
  };

  f32x4 acc[4][4];
  const f32x4 zero4 = {0.f, 0.f, 0.f, 0.f};
#pragma unroll
  for (int m = 0; m < 4; ++m)
#pragma unroll
    for (int n = 0; n < 4; ++n) acc[m][n] = zero4;

  auto compute = [&](int buf) {
    bf16x8 af[4], bfr[4];
#pragma unroll
    for (int m = 0; m < 4; ++m)
      af[m] = *(const bf16x8*)&As[buf][(wm * 64 + m * 16 + lrow) * LSTR + lk];
#pragma unroll
    for (int n = 0; n < 4; ++n)
      bfr[n] = *(const bf16x8*)&Bs[buf][(wn * 64 + n * 16 + lrow) * LSTR + lk];
#pragma unroll
    for (int m = 0; m < 4; ++m)
#pragma unroll
      for (int n = 0; n < 4; ++n)
        acc[m][n] = __builtin_amdgcn_mfma_f32_16x16x32_bf16(af[m], bfr[n], acc[m][n], 0, 0, 0);
  };

  gload(0);
  swrite(0);
  __syncthreads();
  int cur = 0;
#pragma unroll 1
  for (int kt = 0; kt < NKT - 1; ++kt) {
    gload((kt + 1) * BK);    // issue next tile's global loads (hide under MFMA)
    compute(cur);
    swrite(cur ^ 1);         // safe: cur^1 fully consumed before previous barrier
    __syncthreads();
    cur ^= 1;
  }
  compute(cur);

  // epilogue: per 16x16 frag, col = lane&15, row = (lane>>4)*4 + j   [m89-verified]
  const long rbase = m0 + wm * 64 + ((lane >> 4) << 2);
  const long cbase = n0 + wn * 64 + lrow;
#pragma unroll
  for (int m = 0; m < 4; ++m) {
#pragma unroll
    for (int n = 0; n < 4; ++n) {
#pragma unroll
      for (int j = 0; j < 4; ++j) {
        const long row = rbase + m * 16 + j;
        const long col = cbase + n * 16;
        if constexpr (OUT_ATOMIC) {
          atomicAdd(Cf + c_zoff * z + row * ldc + col, acc[m][n][j]);
        } else {
          Cb[c_zoff * z + row * ldc + col] = f2bf(acc[m][n][j]);
        }
      }
    }
  }
}

// ---------------- h'[t, e*I + i] = comb[t,e] * silu(g) * u   (comb folded in)
__global__ __launch_bounds__(256) void silu_kernel(
    const u16* __restrict__ gu, const float* __restrict__ comb,
    u16* __restrict__ hp)
{
  const int c = blockIdx.x * 256 + threadIdx.x;   // grid sized exactly: T*KTOT/8
  const int o0 = c << 3;
  const int t = o0 / KTOT;
  const int r = o0 - t * KTOT;
  const int e = r / IMM;
  const int i0 = r - e * IMM;
  const u16* gp = gu + ((long)(e * T_TOK + t) * TWOI) + i0;
  uint4 gv = *(const uint4*)gp;
  uint4 uv = *(const uint4*)(gp + IMM);
  const float cw = comb[t * NE + e];
  const unsigned* gwv = (const unsigned*)&gv;
  const unsigned* uwv = (const unsigned*)&uv;
  unsigned outw[4];
#pragma unroll
  for (int q = 0; q < 4; ++q) {
    float g0 = bf2f((u16)(gwv[q] & 0xFFFFu));
    float g1 = bf2f((u16)(gwv[q] >> 16));
    float u0 = bf2f((u16)(uwv[q] & 0xFFFFu));
    float u1 = bf2f((u16)(uwv[q] >> 16));
    float h0 = cw * u0 * (g0 / (1.f + __expf(-g0)));
    float h1 = cw * u1 * (g1 / (1.f + __expf(-g1)));
    outw[q] = (unsigned)f2bf(h0) | ((unsigned)f2bf(h1) << 16);
  }
  *(uint4*)(hp + (long)o0) = make_uint4(outw[0], outw[1], outw[2], outw[3]);
}

extern "C" void kernel_launch(void* const* d_in, const int* in_sizes, int n_in,
                              void* d_out, int out_size, void* d_ws, size_t ws_size,
                              hipStream_t stream) {
  const float* hid = (const float*)d_in[0];   // [T, H]
  const float* gw  = (const float*)d_in[1];   // [E, H]
  const float* wgu = (const float*)d_in[2];   // [E, 2I, H]
  const float* wd  = (const float*)d_in[3];   // [E, H, I]
  float* out = (float*)d_out;                 // [T, H] fp32

  // ws layout (~41 MiB total):
  char* ws = (char*)d_ws;
  u16*   hidb = (u16*)ws;                                             // 4 MiB  [T][H] bf16
  float* comb = (float*)(ws + (4l << 20));                            // 32 KiB [T][E] f32
  u16*   gu   = (u16*)(ws + (4l << 20) + (1l << 15));                 // 24 MiB [E][T][2I] bf16
  u16*   hp   = (u16*)(ws + (4l << 20) + (1l << 15)
                          + (long)NE * T_TOK * TWOI * 2);             // 12 MiB [T][E*I] bf16

  hipMemsetAsync(d_out, 0, (size_t)out_size * sizeof(float), stream);
  router_kernel<<<T_TOK, 64, 0, stream>>>(hid, gw, comb);
  cvt_kernel<<<(T_TOK * HID / 4) / 256, 256, 0, stream>>>(hid, hidb);
  // GEMM1: gu[e] = hidden @ wgu[e]^T   (M=1024, N=1536, K=2048) x 8 experts
  gemm_bt<HID, false><<<dim3(T_TOK / 128, TWOI / 128, NE), 256, 0, stream>>>(
      hidb, HID, 0, wgu, (long)TWOI * HID, gu, nullptr, TWOI, (long)T_TOK * TWOI);
  silu_kernel<<<(T_TOK * KTOT / 8) / 256, 256, 0, stream>>>(gu, comb, hp);
  // GEMM2 (split-K by expert): out += h'[:, e*I:(e+1)*I] @ wd[e]^T  (M=1024, N=2048, K=768)
  gemm_bt<IMM, true><<<dim3(T_TOK / 128, HID / 128, NE), 256, 0, stream>>>(
      hp, KTOT, IMM, wd, (long)HID * IMM, nullptr, out, HID, 0);
}